// Round 13
// baseline (405.884 us; speedup 1.0000x reference)
//
#include <hip/hip_runtime.h>
#include <hip/hip_cooperative_groups.h>

namespace cg = cooperative_groups;

// hnode_prompt_layer_feature_cat_edge
// out[d, 0:128]   = (sum_{e: dst[e]=d} emb[src[e]]) * w
// out[d, 128:160] =  sum_{e: dst[e]=d} e_feat[e]
//
// R13: ONE cooperative kernel fusing {zero cursor -> place -> gather -> ovf}
// with 3 grid.sync()s. Removes 3 dispatch gaps + memset dispatch from the
// captured graph. Gather phase = R12's proven node body in a wave-stride
// loop. Falls back to the R12 4-dispatch path if cooperative launch is
// rejected (validation error at capture time).

#define D_FT 128
#define D_E 32
#define D_OUT (D_FT + D_E)
#define CAP 32

typedef float f32x4 __attribute__((ext_vector_type(4)));
typedef int   i32x2 __attribute__((ext_vector_type(2)));

// ---------------- fused cooperative kernel ----------------
__global__ __launch_bounds__(256, 8)
void fused_kernel(const float* __restrict__ emb,
                  const float* __restrict__ e_feat,
                  const float* __restrict__ w,
                  const int* __restrict__ src_idx,
                  const int* __restrict__ dst_idx,
                  int* __restrict__ cursor,
                  i32x2* __restrict__ bucket,
                  int* __restrict__ ovf,
                  int* __restrict__ ovf_cnt,
                  float* __restrict__ out,
                  int N, int E) {
    cg::grid_group grid = cg::this_grid();
    const int tid = blockIdx.x * blockDim.x + threadIdx.x;
    const int gsz = gridDim.x * blockDim.x;

    // ---- phase 0: zero cursor[N] + ovf_cnt + pad ----
    for (int i = tid; i < N + 2; i += gsz) cursor[i] = 0;
    grid.sync();

    // ---- phase 1: place edges into buckets ----
    for (int i = tid; i < E; i += gsz) {
        int d = dst_idx[i];
        int slot = atomicAdd(&cursor[d], 1);
        if (slot < CAP) {
            i32x2 pr; pr.x = src_idx[i]; pr.y = i;
            bucket[(size_t)d * CAP + slot] = pr;
        } else {
            int p = atomicAdd(ovf_cnt, 1);
            ovf[p] = i;
        }
    }
    grid.sync();

    // ---- phase 2: gather (R12 body, wave-stride over nodes) ----
    {
        const int wid     = tid >> 6;
        const int wstride = gsz >> 6;
        const int lane = threadIdx.x & 63;
        const int half = lane >> 5;
        const int q    = lane & 31;
        const int qg   = q >> 3;
        const int ql   = q & 7;
        const float4 wv = *reinterpret_cast<const float4*>(w + q * 4);

        for (int g = wid; g < N; g += wstride) {
            i32x2 pr = __builtin_nontemporal_load(&bucket[(size_t)g * CAP + (lane & 31)]);
            int cnt = cursor[g];
            cnt = cnt > CAP ? CAP : cnt;

            float4 accft = make_float4(0.f, 0.f, 0.f, 0.f);
            float4 acce  = make_float4(0.f, 0.f, 0.f, 0.f);

            int i = 0;
            if (cnt >= 8) {
                int b  = (half << 2);
                int s0 = __shfl(pr.x, b + 0, 64);
                int s1 = __shfl(pr.x, b + 1, 64);
                int s2 = __shfl(pr.x, b + 2, 64);
                int s3 = __shfl(pr.x, b + 3, 64);
                int ee = __shfl(pr.y, b + qg, 64);
                float4 v0 = *reinterpret_cast<const float4*>(emb + (size_t)s0 * D_FT + q * 4);
                float4 v1 = *reinterpret_cast<const float4*>(emb + (size_t)s1 * D_FT + q * 4);
                float4 v2 = *reinterpret_cast<const float4*>(emb + (size_t)s2 * D_FT + q * 4);
                float4 v3 = *reinterpret_cast<const float4*>(emb + (size_t)s3 * D_FT + q * 4);
                f32x4 a = __builtin_nontemporal_load(
                    reinterpret_cast<const f32x4*>(e_feat + (size_t)ee * D_E + ql * 4));

                for (i = 8; i + 8 <= cnt; i += 8) {
                    int b2 = i + (half << 2);
                    int t0 = __shfl(pr.x, b2 + 0, 64);
                    int t1 = __shfl(pr.x, b2 + 1, 64);
                    int t2 = __shfl(pr.x, b2 + 2, 64);
                    int t3 = __shfl(pr.x, b2 + 3, 64);
                    int e2 = __shfl(pr.y, b2 + qg, 64);
                    float4 u0 = *reinterpret_cast<const float4*>(emb + (size_t)t0 * D_FT + q * 4);
                    float4 u1 = *reinterpret_cast<const float4*>(emb + (size_t)t1 * D_FT + q * 4);
                    float4 u2 = *reinterpret_cast<const float4*>(emb + (size_t)t2 * D_FT + q * 4);
                    float4 u3 = *reinterpret_cast<const float4*>(emb + (size_t)t3 * D_FT + q * 4);
                    f32x4 a2 = __builtin_nontemporal_load(
                        reinterpret_cast<const f32x4*>(e_feat + (size_t)e2 * D_E + ql * 4));
                    accft.x += (v0.x + v1.x) + (v2.x + v3.x);
                    accft.y += (v0.y + v1.y) + (v2.y + v3.y);
                    accft.z += (v0.z + v1.z) + (v2.z + v3.z);
                    accft.w += (v0.w + v1.w) + (v2.w + v3.w);
                    acce.x += a.x; acce.y += a.y; acce.z += a.z; acce.w += a.w;
                    v0 = u0; v1 = u1; v2 = u2; v3 = u3; a = a2;
                }
                accft.x += (v0.x + v1.x) + (v2.x + v3.x);
                accft.y += (v0.y + v1.y) + (v2.y + v3.y);
                accft.z += (v0.z + v1.z) + (v2.z + v3.z);
                accft.w += (v0.w + v1.w) + (v2.w + v3.w);
                acce.x += a.x; acce.y += a.y; acce.z += a.z; acce.w += a.w;
            }
            if (i < cnt) {
                const int c1 = cnt - 1;
                int b  = i + (half << 2);
                int t0 = b + 0, t1 = b + 1, t2 = b + 2, t3 = b + 3, te = b + qg;
                int s0 = __shfl(pr.x, t0 < c1 ? t0 : c1, 64);
                int s1 = __shfl(pr.x, t1 < c1 ? t1 : c1, 64);
                int s2 = __shfl(pr.x, t2 < c1 ? t2 : c1, 64);
                int s3 = __shfl(pr.x, t3 < c1 ? t3 : c1, 64);
                int ee = __shfl(pr.y, te < c1 ? te : c1, 64);
                float4 v0 = *reinterpret_cast<const float4*>(emb + (size_t)s0 * D_FT + q * 4);
                float4 v1 = *reinterpret_cast<const float4*>(emb + (size_t)s1 * D_FT + q * 4);
                float4 v2 = *reinterpret_cast<const float4*>(emb + (size_t)s2 * D_FT + q * 4);
                float4 v3 = *reinterpret_cast<const float4*>(emb + (size_t)s3 * D_FT + q * 4);
                f32x4 a = __builtin_nontemporal_load(
                    reinterpret_cast<const f32x4*>(e_feat + (size_t)ee * D_E + ql * 4));
                float m0 = (t0 < cnt) ? 1.f : 0.f;
                float m1 = (t1 < cnt) ? 1.f : 0.f;
                float m2 = (t2 < cnt) ? 1.f : 0.f;
                float m3 = (t3 < cnt) ? 1.f : 0.f;
                float me = (te < cnt) ? 1.f : 0.f;
                accft.x = fmaf(v0.x, m0, accft.x); accft.y = fmaf(v0.y, m0, accft.y);
                accft.z = fmaf(v0.z, m0, accft.z); accft.w = fmaf(v0.w, m0, accft.w);
                accft.x = fmaf(v1.x, m1, accft.x); accft.y = fmaf(v1.y, m1, accft.y);
                accft.z = fmaf(v1.z, m1, accft.z); accft.w = fmaf(v1.w, m1, accft.w);
                accft.x = fmaf(v2.x, m2, accft.x); accft.y = fmaf(v2.y, m2, accft.y);
                accft.z = fmaf(v2.z, m2, accft.z); accft.w = fmaf(v2.w, m2, accft.w);
                accft.x = fmaf(v3.x, m3, accft.x); accft.y = fmaf(v3.y, m3, accft.y);
                accft.z = fmaf(v3.z, m3, accft.z); accft.w = fmaf(v3.w, m3, accft.w);
                acce.x = fmaf(a.x, me, acce.x); acce.y = fmaf(a.y, me, acce.y);
                acce.z = fmaf(a.z, me, acce.z); acce.w = fmaf(a.w, me, acce.w);
            }

            accft.x += __shfl_xor(accft.x, 32, 64);
            accft.y += __shfl_xor(accft.y, 32, 64);
            accft.z += __shfl_xor(accft.z, 32, 64);
            accft.w += __shfl_xor(accft.w, 32, 64);
            acce.x += __shfl_xor(acce.x, 8, 64);
            acce.y += __shfl_xor(acce.y, 8, 64);
            acce.z += __shfl_xor(acce.z, 8, 64);
            acce.w += __shfl_xor(acce.w, 8, 64);
            acce.x += __shfl_xor(acce.x, 16, 64);
            acce.y += __shfl_xor(acce.y, 16, 64);
            acce.z += __shfl_xor(acce.z, 16, 64);
            acce.w += __shfl_xor(acce.w, 16, 64);
            acce.x += __shfl_xor(acce.x, 32, 64);
            acce.y += __shfl_xor(acce.y, 32, 64);
            acce.z += __shfl_xor(acce.z, 32, 64);
            acce.w += __shfl_xor(acce.w, 32, 64);

            if (half == 0) {
                float* o = out + (size_t)g * D_OUT;
                f32x4 r; r.x = accft.x * wv.x; r.y = accft.y * wv.y;
                         r.z = accft.z * wv.z; r.w = accft.w * wv.w;
                __builtin_nontemporal_store(r, reinterpret_cast<f32x4*>(o + q * 4));
                if (q < 8) {
                    f32x4 re; re.x = acce.x; re.y = acce.y; re.z = acce.z; re.w = acce.w;
                    __builtin_nontemporal_store(re, reinterpret_cast<f32x4*>(o + D_FT + q * 4));
                }
            }
        }
    }
    grid.sync();

    // ---- phase 3: drain overflow (deg > CAP; ~never for this data) ----
    {
        int n = *ovf_cnt;
        int total = n * 40;
        for (int t = tid; t < total; t += gsz) {
            int e = t / 40, slot = t % 40;
            int eid = ovf[e];
            int d = dst_idx[eid];
            float* o = out + (size_t)d * D_OUT;
            if (slot < 32) {
                int s = src_idx[eid];
                float4 v  = *reinterpret_cast<const float4*>(emb + (size_t)s * D_FT + slot * 4);
                float4 wv = *reinterpret_cast<const float4*>(w + slot * 4);
                atomicAdd(o + slot * 4 + 0, v.x * wv.x);
                atomicAdd(o + slot * 4 + 1, v.y * wv.y);
                atomicAdd(o + slot * 4 + 2, v.z * wv.z);
                atomicAdd(o + slot * 4 + 3, v.w * wv.w);
            } else {
                int qq = slot - 32;
                float4 ve = *reinterpret_cast<const float4*>(e_feat + (size_t)eid * D_E + qq * 4);
                atomicAdd(o + D_FT + qq * 4 + 0, ve.x);
                atomicAdd(o + D_FT + qq * 4 + 1, ve.y);
                atomicAdd(o + D_FT + qq * 4 + 2, ve.z);
                atomicAdd(o + D_FT + qq * 4 + 3, ve.w);
            }
        }
    }
}

// ---------------- R12 fallback kernels (used if cooperative launch fails) ----------------
__global__ void place_bucket_kernel(const int* __restrict__ src_idx,
                                    const int* __restrict__ dst_idx,
                                    int* __restrict__ cursor,
                                    i32x2* __restrict__ bucket,
                                    int* __restrict__ ovf,
                                    int* __restrict__ ovf_cnt, int E) {
    int i = blockIdx.x * blockDim.x + threadIdx.x;
    if (i >= E) return;
    int d = dst_idx[i];
    int slot = atomicAdd(&cursor[d], 1);
    if (slot < CAP) {
        i32x2 pr; pr.x = src_idx[i]; pr.y = i;
        bucket[(size_t)d * CAP + slot] = pr;
    } else {
        int p = atomicAdd(ovf_cnt, 1);
        ovf[p] = i;
    }
}

__global__ void gather_bucket_kernel(const float* __restrict__ emb,
                                     const float* __restrict__ e_feat,
                                     const float* __restrict__ w,
                                     const int* __restrict__ cursor,
                                     const i32x2* __restrict__ bucket,
                                     float* __restrict__ out, int N) {
    int g = (blockIdx.x * blockDim.x + threadIdx.x) >> 6;
    if (g >= N) return;
    const int lane = threadIdx.x & 63;
    const int half = lane >> 5;
    const int q    = lane & 31;
    const int qg   = q >> 3;
    const int ql   = q & 7;

    i32x2 pr = __builtin_nontemporal_load(&bucket[(size_t)g * CAP + (lane & 31)]);
    int cnt = cursor[g];
    cnt = cnt > CAP ? CAP : cnt;

    float4 accft = make_float4(0.f, 0.f, 0.f, 0.f);
    float4 acce  = make_float4(0.f, 0.f, 0.f, 0.f);

    int i = 0;
    if (cnt >= 8) {
        int b  = (half << 2);
        int s0 = __shfl(pr.x, b + 0, 64);
        int s1 = __shfl(pr.x, b + 1, 64);
        int s2 = __shfl(pr.x, b + 2, 64);
        int s3 = __shfl(pr.x, b + 3, 64);
        int ee = __shfl(pr.y, b + qg, 64);
        float4 v0 = *reinterpret_cast<const float4*>(emb + (size_t)s0 * D_FT + q * 4);
        float4 v1 = *reinterpret_cast<const float4*>(emb + (size_t)s1 * D_FT + q * 4);
        float4 v2 = *reinterpret_cast<const float4*>(emb + (size_t)s2 * D_FT + q * 4);
        float4 v3 = *reinterpret_cast<const float4*>(emb + (size_t)s3 * D_FT + q * 4);
        f32x4 a = __builtin_nontemporal_load(
            reinterpret_cast<const f32x4*>(e_feat + (size_t)ee * D_E + ql * 4));
        for (i = 8; i + 8 <= cnt; i += 8) {
            int b2 = i + (half << 2);
            int t0 = __shfl(pr.x, b2 + 0, 64);
            int t1 = __shfl(pr.x, b2 + 1, 64);
            int t2 = __shfl(pr.x, b2 + 2, 64);
            int t3 = __shfl(pr.x, b2 + 3, 64);
            int e2 = __shfl(pr.y, b2 + qg, 64);
            float4 u0 = *reinterpret_cast<const float4*>(emb + (size_t)t0 * D_FT + q * 4);
            float4 u1 = *reinterpret_cast<const float4*>(emb + (size_t)t1 * D_FT + q * 4);
            float4 u2 = *reinterpret_cast<const float4*>(emb + (size_t)t2 * D_FT + q * 4);
            float4 u3 = *reinterpret_cast<const float4*>(emb + (size_t)t3 * D_FT + q * 4);
            f32x4 a2 = __builtin_nontemporal_load(
                reinterpret_cast<const f32x4*>(e_feat + (size_t)e2 * D_E + ql * 4));
            accft.x += (v0.x + v1.x) + (v2.x + v3.x);
            accft.y += (v0.y + v1.y) + (v2.y + v3.y);
            accft.z += (v0.z + v1.z) + (v2.z + v3.z);
            accft.w += (v0.w + v1.w) + (v2.w + v3.w);
            acce.x += a.x; acce.y += a.y; acce.z += a.z; acce.w += a.w;
            v0 = u0; v1 = u1; v2 = u2; v3 = u3; a = a2;
        }
        accft.x += (v0.x + v1.x) + (v2.x + v3.x);
        accft.y += (v0.y + v1.y) + (v2.y + v3.y);
        accft.z += (v0.z + v1.z) + (v2.z + v3.z);
        accft.w += (v0.w + v1.w) + (v2.w + v3.w);
        acce.x += a.x; acce.y += a.y; acce.z += a.z; acce.w += a.w;
    }
    if (i < cnt) {
        const int c1 = cnt - 1;
        int b  = i + (half << 2);
        int t0 = b + 0, t1 = b + 1, t2 = b + 2, t3 = b + 3, te = b + qg;
        int s0 = __shfl(pr.x, t0 < c1 ? t0 : c1, 64);
        int s1 = __shfl(pr.x, t1 < c1 ? t1 : c1, 64);
        int s2 = __shfl(pr.x, t2 < c1 ? t2 : c1, 64);
        int s3 = __shfl(pr.x, t3 < c1 ? t3 : c1, 64);
        int ee = __shfl(pr.y, te < c1 ? te : c1, 64);
        float4 v0 = *reinterpret_cast<const float4*>(emb + (size_t)s0 * D_FT + q * 4);
        float4 v1 = *reinterpret_cast<const float4*>(emb + (size_t)s1 * D_FT + q * 4);
        float4 v2 = *reinterpret_cast<const float4*>(emb + (size_t)s2 * D_FT + q * 4);
        float4 v3 = *reinterpret_cast<const float4*>(emb + (size_t)s3 * D_FT + q * 4);
        f32x4 a = __builtin_nontemporal_load(
            reinterpret_cast<const f32x4*>(e_feat + (size_t)ee * D_E + ql * 4));
        float m0 = (t0 < cnt) ? 1.f : 0.f;
        float m1 = (t1 < cnt) ? 1.f : 0.f;
        float m2 = (t2 < cnt) ? 1.f : 0.f;
        float m3 = (t3 < cnt) ? 1.f : 0.f;
        float me = (te < cnt) ? 1.f : 0.f;
        accft.x = fmaf(v0.x, m0, accft.x); accft.y = fmaf(v0.y, m0, accft.y);
        accft.z = fmaf(v0.z, m0, accft.z); accft.w = fmaf(v0.w, m0, accft.w);
        accft.x = fmaf(v1.x, m1, accft.x); accft.y = fmaf(v1.y, m1, accft.y);
        accft.z = fmaf(v1.z, m1, accft.z); accft.w = fmaf(v1.w, m1, accft.w);
        accft.x = fmaf(v2.x, m2, accft.x); accft.y = fmaf(v2.y, m2, accft.y);
        accft.z = fmaf(v2.z, m2, accft.z); accft.w = fmaf(v2.w, m2, accft.w);
        accft.x = fmaf(v3.x, m3, accft.x); accft.y = fmaf(v3.y, m3, accft.y);
        accft.z = fmaf(v3.z, m3, accft.z); accft.w = fmaf(v3.w, m3, accft.w);
        acce.x = fmaf(a.x, me, acce.x); acce.y = fmaf(a.y, me, acce.y);
        acce.z = fmaf(a.z, me, acce.z); acce.w = fmaf(a.w, me, acce.w);
    }

    accft.x += __shfl_xor(accft.x, 32, 64);
    accft.y += __shfl_xor(accft.y, 32, 64);
    accft.z += __shfl_xor(accft.z, 32, 64);
    accft.w += __shfl_xor(accft.w, 32, 64);
    acce.x += __shfl_xor(acce.x, 8, 64);
    acce.y += __shfl_xor(acce.y, 8, 64);
    acce.z += __shfl_xor(acce.z, 8, 64);
    acce.w += __shfl_xor(acce.w, 8, 64);
    acce.x += __shfl_xor(acce.x, 16, 64);
    acce.y += __shfl_xor(acce.y, 16, 64);
    acce.z += __shfl_xor(acce.z, 16, 64);
    acce.w += __shfl_xor(acce.w, 16, 64);
    acce.x += __shfl_xor(acce.x, 32, 64);
    acce.y += __shfl_xor(acce.y, 32, 64);
    acce.z += __shfl_xor(acce.z, 32, 64);
    acce.w += __shfl_xor(acce.w, 32, 64);

    if (half == 0) {
        float4 wv = *reinterpret_cast<const float4*>(w + q * 4);
        float* o = out + (size_t)g * D_OUT;
        f32x4 r; r.x = accft.x * wv.x; r.y = accft.y * wv.y;
                 r.z = accft.z * wv.z; r.w = accft.w * wv.w;
        __builtin_nontemporal_store(r, reinterpret_cast<f32x4*>(o + q * 4));
        if (q < 8) {
            f32x4 re; re.x = acce.x; re.y = acce.y; re.z = acce.z; re.w = acce.w;
            __builtin_nontemporal_store(re, reinterpret_cast<f32x4*>(o + D_FT + q * 4));
        }
    }
}

__global__ void ovf_scatter_kernel(const float* __restrict__ emb,
                                   const float* __restrict__ e_feat,
                                   const float* __restrict__ w,
                                   const int* __restrict__ src_idx,
                                   const int* __restrict__ dst_idx,
                                   const int* __restrict__ ovf,
                                   const int* __restrict__ ovf_cnt,
                                   float* __restrict__ out) {
    int n = *ovf_cnt;
    int total = n * 40;
    for (int t = blockIdx.x * blockDim.x + threadIdx.x; t < total;
         t += gridDim.x * blockDim.x) {
        int e = t / 40, slot = t % 40;
        int eid = ovf[e];
        int d = dst_idx[eid];
        float* o = out + (size_t)d * D_OUT;
        if (slot < 32) {
            int s = src_idx[eid];
            float4 v  = *reinterpret_cast<const float4*>(emb + (size_t)s * D_FT + slot * 4);
            float4 wv = *reinterpret_cast<const float4*>(w + slot * 4);
            atomicAdd(o + slot * 4 + 0, v.x * wv.x);
            atomicAdd(o + slot * 4 + 1, v.y * wv.y);
            atomicAdd(o + slot * 4 + 2, v.z * wv.z);
            atomicAdd(o + slot * 4 + 3, v.w * wv.w);
        } else {
            int qq = slot - 32;
            float4 ve = *reinterpret_cast<const float4*>(e_feat + (size_t)eid * D_E + qq * 4);
            atomicAdd(o + D_FT + qq * 4 + 0, ve.x);
            atomicAdd(o + D_FT + qq * 4 + 1, ve.y);
            atomicAdd(o + D_FT + qq * 4 + 2, ve.z);
            atomicAdd(o + D_FT + qq * 4 + 3, ve.w);
        }
    }
}

// ---- last-resort fallback (R1 atomic path) if ws too small ----
__global__ void scatter_ft_kernel(const float* __restrict__ emb, const float* __restrict__ w,
                                  const int* __restrict__ src_idx, const int* __restrict__ dst_idx,
                                  float* __restrict__ out, int n_items) {
    int idx = blockIdx.x * blockDim.x + threadIdx.x;
    if (idx >= n_items) return;
    int e = idx >> 5, q = idx & 31;
    int s = src_idx[e], d = dst_idx[e];
    const float4 v  = *reinterpret_cast<const float4*>(emb + (size_t)s * D_FT + q * 4);
    const float4 wv = *reinterpret_cast<const float4*>(w + q * 4);
    float* o = out + (size_t)d * D_OUT + q * 4;
    atomicAdd(o + 0, v.x * wv.x); atomicAdd(o + 1, v.y * wv.y);
    atomicAdd(o + 2, v.z * wv.z); atomicAdd(o + 3, v.w * wv.w);
}
__global__ void scatter_e_kernel(const float* __restrict__ e_feat, const int* __restrict__ dst_idx,
                                 float* __restrict__ out, int n_items) {
    int idx = blockIdx.x * blockDim.x + threadIdx.x;
    if (idx >= n_items) return;
    int e = idx >> 3, q = idx & 7;
    int d = dst_idx[e];
    const float4 v = *reinterpret_cast<const float4*>(e_feat + (size_t)e * D_E + q * 4);
    float* o = out + (size_t)d * D_OUT + D_FT + q * 4;
    atomicAdd(o + 0, v.x); atomicAdd(o + 1, v.y);
    atomicAdd(o + 2, v.z); atomicAdd(o + 3, v.w);
}

extern "C" void kernel_launch(void* const* d_in, const int* in_sizes, int n_in,
                              void* d_out, int out_size, void* d_ws, size_t ws_size,
                              hipStream_t stream) {
    const float* emb    = (const float*)d_in[0];   // [N, 128]
    const float* e_feat = (const float*)d_in[1];   // [E, 32]
    const float* w      = (const float*)d_in[2];   // [1, 128]
    const int*   src    = (const int*)d_in[3];     // [E]
    const int*   dst    = (const int*)d_in[4];     // [E]
    float* out = (float*)d_out;                    // [N, 160]

    int E = in_sizes[3];
    int N = out_size / D_OUT;

    // ws layout: cursor[N] | ovf_cnt[1] | pad[1] | bucket[N*CAP] i32x2 | ovf[E]
    size_t ints_head = (size_t)N + 2;
    size_t need = ints_head * 4 + (size_t)N * CAP * 8 + (size_t)E * 4;

    if (ws_size >= need) {
        int*   cursor  = (int*)d_ws;
        int*   ovf_cnt = cursor + N;
        i32x2* bucket  = (i32x2*)(cursor + ints_head);
        int*   ovf     = (int*)(bucket + (size_t)N * CAP);

        // ---- try the fused cooperative kernel ----
        int dev = 0;
        hipGetDevice(&dev);
        int numCU = 256;
        hipDeviceGetAttribute(&numCU, hipDeviceAttributeMultiprocessorCount, dev);
        int blocksPerCU = 0;
        hipError_t occErr = hipOccupancyMaxActiveBlocksPerMultiprocessor(
            &blocksPerCU, (const void*)fused_kernel, 256, 0);
        int grid = (occErr == hipSuccess && blocksPerCU > 0) ? blocksPerCU * numCU : 1024;
        if (grid > 4096) grid = 4096;

        void* kargs[] = {(void*)&emb, (void*)&e_feat, (void*)&w, (void*)&src,
                         (void*)&dst, (void*)&cursor, (void*)&bucket, (void*)&ovf,
                         (void*)&ovf_cnt, (void*)&out, (void*)&N, (void*)&E};
        hipError_t lerr = hipLaunchCooperativeKernel(
            (const void*)fused_kernel, dim3(grid), dim3(256), kargs, 0, stream);

        if (lerr != hipSuccess) {
            // ---- fallback: proven R12 4-dispatch path ----
            hipMemsetAsync(cursor, 0, ints_head * sizeof(int), stream);
            place_bucket_kernel<<<(E + 255) / 256, 256, 0, stream>>>(
                src, dst, cursor, bucket, ovf, ovf_cnt, E);
            gather_bucket_kernel<<<((size_t)N * 64 + 255) / 256, 256, 0, stream>>>(
                emb, e_feat, w, cursor, bucket, out, N);
            ovf_scatter_kernel<<<128, 256, 0, stream>>>(
                emb, e_feat, w, src, dst, ovf, ovf_cnt, out);
        }
    } else {
        hipMemsetAsync(d_out, 0, (size_t)out_size * sizeof(float), stream);
        int items_ft = E * 32, items_e = E * 8;
        scatter_ft_kernel<<<(items_ft + 255) / 256, 256, 0, stream>>>(emb, w, src, dst, out, items_ft);
        scatter_e_kernel<<<(items_e + 255) / 256, 256, 0, stream>>>(e_feat, dst, out, items_e);
    }
}

// Round 14
// 99.965 us; speedup vs baseline: 4.0603x; 4.0603x over previous
//
#include <hip/hip_runtime.h>

// hnode_prompt_layer_feature_cat_edge
// out[d, 0:128]   = (sum_{e: dst[e]=d} emb[src[e]]) * w
// out[d, 128:160] =  sum_{e: dst[e]=d} e_feat[e]
//
// R14 = R12 (best structure) minus the ovf dispatch:
//  - ovf drain folded into gather as a COLD wave-uniform branch
//    (cnt_raw > CAP, ~never taken at deg~Poisson(12), CAP=32). The node's
//    own wave accumulates its overflow edges before its single store ->
//    no atomics, no race, one fewer dispatch + gap.
//    Drain runs on half==0 lanes only: accft/acce are reduced across
//    halves (xor 32) at the end, so a both-halves drain would double-count.
//  - bucket head load is a REGULAR load (was nontemporal): bucket is
//    L2/L3-resident (written by place one dispatch earlier); nt bypassed
//    that and lengthened every wave's head chain. nt stays on e_feat
//    (streamed once) and on out stores (write-combine).
//  - R13 lesson: grid.sync() cooperative fusion costs ~500us at this grid
//    size on MI355X (cross-XCD barrier protocol) — never again.

#define D_FT 128
#define D_E 32
#define D_OUT (D_FT + D_E)
#define CAP 32

typedef float f32x4 __attribute__((ext_vector_type(4)));
typedef int   i32x2 __attribute__((ext_vector_type(2)));

__global__ void place_bucket_kernel(const int* __restrict__ src_idx,
                                    const int* __restrict__ dst_idx,
                                    int* __restrict__ cursor,
                                    i32x2* __restrict__ bucket,
                                    int* __restrict__ ovf,
                                    int* __restrict__ ovf_cnt, int E) {
    int i = blockIdx.x * blockDim.x + threadIdx.x;
    if (i >= E) return;
    int d = dst_idx[i];
    int slot = atomicAdd(&cursor[d], 1);
    if (slot < CAP) {
        i32x2 pr; pr.x = src_idx[i]; pr.y = i;
        bucket[(size_t)d * CAP + slot] = pr;
    } else {
        int p = atomicAdd(ovf_cnt, 1);
        ovf[p] = i;
    }
}

__global__ void gather_bucket_kernel(const float* __restrict__ emb,
                                     const float* __restrict__ e_feat,
                                     const float* __restrict__ w,
                                     const int* __restrict__ cursor,
                                     const i32x2* __restrict__ bucket,
                                     const int* __restrict__ src_idx,
                                     const int* __restrict__ dst_idx,
                                     const int* __restrict__ ovf,
                                     const int* __restrict__ ovf_cnt,
                                     float* __restrict__ out, int N) {
    int g = (blockIdx.x * blockDim.x + threadIdx.x) >> 6;   // node = one wave
    if (g >= N) return;                                     // wave-uniform exit
    const int lane = threadIdx.x & 63;
    const int half = lane >> 5;      // 0/1: which 4-edge slice of the 8/iter
    const int q    = lane & 31;      // float4 slot within the 128-wide row
    const int qg   = q >> 3;         // e_feat edge-subgroup 0..3 within half
    const int ql   = q & 7;          // float4 slot within e_feat row

    // cursor load and bucket load issue INDEPENDENTLY (no guard on bucket).
    // Regular load: bucket is L2/L3-resident from place. Slots >= cnt hold
    // stale data but are never consumed (clamped sources, masked loads).
    i32x2 pr = bucket[(size_t)g * CAP + (lane & 31)];
    int cnt_raw = cursor[g];
    int cnt = cnt_raw > CAP ? CAP : cnt_raw;

    float4 accft = make_float4(0.f, 0.f, 0.f, 0.f);
    float4 acce  = make_float4(0.f, 0.f, 0.f, 0.f);  // partial for (half,qg)

    int i = 0;
    if (cnt >= 8) {
        // ---- prologue: block 0's loads in flight ----
        int b  = (half << 2);
        int s0 = __shfl(pr.x, b + 0, 64);
        int s1 = __shfl(pr.x, b + 1, 64);
        int s2 = __shfl(pr.x, b + 2, 64);
        int s3 = __shfl(pr.x, b + 3, 64);
        int ee = __shfl(pr.y, b + qg, 64);
        float4 v0 = *reinterpret_cast<const float4*>(emb + (size_t)s0 * D_FT + q * 4);
        float4 v1 = *reinterpret_cast<const float4*>(emb + (size_t)s1 * D_FT + q * 4);
        float4 v2 = *reinterpret_cast<const float4*>(emb + (size_t)s2 * D_FT + q * 4);
        float4 v3 = *reinterpret_cast<const float4*>(emb + (size_t)s3 * D_FT + q * 4);
        f32x4 a = __builtin_nontemporal_load(
            reinterpret_cast<const f32x4*>(e_feat + (size_t)ee * D_E + ql * 4));

        for (i = 8; i + 8 <= cnt; i += 8) {
            // ---- issue block i's loads BEFORE consuming block i-8 ----
            int b2 = i + (half << 2);
            int t0 = __shfl(pr.x, b2 + 0, 64);
            int t1 = __shfl(pr.x, b2 + 1, 64);
            int t2 = __shfl(pr.x, b2 + 2, 64);
            int t3 = __shfl(pr.x, b2 + 3, 64);
            int e2 = __shfl(pr.y, b2 + qg, 64);
            float4 u0 = *reinterpret_cast<const float4*>(emb + (size_t)t0 * D_FT + q * 4);
            float4 u1 = *reinterpret_cast<const float4*>(emb + (size_t)t1 * D_FT + q * 4);
            float4 u2 = *reinterpret_cast<const float4*>(emb + (size_t)t2 * D_FT + q * 4);
            float4 u3 = *reinterpret_cast<const float4*>(emb + (size_t)t3 * D_FT + q * 4);
            f32x4 a2 = __builtin_nontemporal_load(
                reinterpret_cast<const f32x4*>(e_feat + (size_t)e2 * D_E + ql * 4));
            // ---- accumulate block i-8 (waits only on the older 5 loads) ----
            accft.x += (v0.x + v1.x) + (v2.x + v3.x);
            accft.y += (v0.y + v1.y) + (v2.y + v3.y);
            accft.z += (v0.z + v1.z) + (v2.z + v3.z);
            accft.w += (v0.w + v1.w) + (v2.w + v3.w);
            acce.x += a.x; acce.y += a.y; acce.z += a.z; acce.w += a.w;
            v0 = u0; v1 = u1; v2 = u2; v3 = u3; a = a2;
        }
        // ---- epilogue: accumulate the last in-flight block ----
        accft.x += (v0.x + v1.x) + (v2.x + v3.x);
        accft.y += (v0.y + v1.y) + (v2.y + v3.y);
        accft.z += (v0.z + v1.z) + (v2.z + v3.z);
        accft.w += (v0.w + v1.w) + (v2.w + v3.w);
        acce.x += a.x; acce.y += a.y; acce.z += a.z; acce.w += a.w;
    }
    // Remainder (cnt - i in [1,7] when taken): ONE masked full-width block.
    if (i < cnt) {
        const int c1 = cnt - 1;
        int b  = i + (half << 2);
        int t0 = b + 0, t1 = b + 1, t2 = b + 2, t3 = b + 3, te = b + qg;
        int s0 = __shfl(pr.x, t0 < c1 ? t0 : c1, 64);
        int s1 = __shfl(pr.x, t1 < c1 ? t1 : c1, 64);
        int s2 = __shfl(pr.x, t2 < c1 ? t2 : c1, 64);
        int s3 = __shfl(pr.x, t3 < c1 ? t3 : c1, 64);
        int ee = __shfl(pr.y, te < c1 ? te : c1, 64);
        float4 v0 = *reinterpret_cast<const float4*>(emb + (size_t)s0 * D_FT + q * 4);
        float4 v1 = *reinterpret_cast<const float4*>(emb + (size_t)s1 * D_FT + q * 4);
        float4 v2 = *reinterpret_cast<const float4*>(emb + (size_t)s2 * D_FT + q * 4);
        float4 v3 = *reinterpret_cast<const float4*>(emb + (size_t)s3 * D_FT + q * 4);
        f32x4 a = __builtin_nontemporal_load(
            reinterpret_cast<const f32x4*>(e_feat + (size_t)ee * D_E + ql * 4));
        float m0 = (t0 < cnt) ? 1.f : 0.f;
        float m1 = (t1 < cnt) ? 1.f : 0.f;
        float m2 = (t2 < cnt) ? 1.f : 0.f;
        float m3 = (t3 < cnt) ? 1.f : 0.f;
        float me = (te < cnt) ? 1.f : 0.f;
        accft.x = fmaf(v0.x, m0, accft.x); accft.y = fmaf(v0.y, m0, accft.y);
        accft.z = fmaf(v0.z, m0, accft.z); accft.w = fmaf(v0.w, m0, accft.w);
        accft.x = fmaf(v1.x, m1, accft.x); accft.y = fmaf(v1.y, m1, accft.y);
        accft.z = fmaf(v1.z, m1, accft.z); accft.w = fmaf(v1.w, m1, accft.w);
        accft.x = fmaf(v2.x, m2, accft.x); accft.y = fmaf(v2.y, m2, accft.y);
        accft.z = fmaf(v2.z, m2, accft.z); accft.w = fmaf(v2.w, m2, accft.w);
        accft.x = fmaf(v3.x, m3, accft.x); accft.y = fmaf(v3.y, m3, accft.y);
        accft.z = fmaf(v3.z, m3, accft.z); accft.w = fmaf(v3.w, m3, accft.w);
        acce.x = fmaf(a.x, me, acce.x); acce.y = fmaf(a.y, me, acce.y);
        acce.z = fmaf(a.z, me, acce.z); acce.w = fmaf(a.w, me, acce.w);
    }

    // ---- COLD: drain this node's overflow edges (raw degree > CAP) ----
    // Wave-uniform branch, ~never taken. half==0 lanes only: accft/acce are
    // combined across halves below (xor 32), so both halves draining would
    // double-count. No atomics: contribution lands in this wave's registers
    // before its single store.
    if (cnt_raw > CAP) {
        int n = *ovf_cnt;
        for (int k = 0; k < n; ++k) {
            int eid = ovf[k];
            if (dst_idx[eid] == g && half == 0) {
                int s = src_idx[eid];
                float4 v = *reinterpret_cast<const float4*>(emb + (size_t)s * D_FT + q * 4);
                accft.x += v.x; accft.y += v.y; accft.z += v.z; accft.w += v.w;
                if (q < 8) {   // qg==0, ql==q: slot-q partial, summed by xor 8/16
                    f32x4 a = *reinterpret_cast<const f32x4*>(e_feat + (size_t)eid * D_E + q * 4);
                    acce.x += a.x; acce.y += a.y; acce.z += a.z; acce.w += a.w;
                }
            }
        }
    }

    // combine the two halves' ft partials
    accft.x += __shfl_xor(accft.x, 32, 64);
    accft.y += __shfl_xor(accft.y, 32, 64);
    accft.z += __shfl_xor(accft.z, 32, 64);
    accft.w += __shfl_xor(accft.w, 32, 64);
    // combine e partials: across qg (8,16) then across halves (32)
    acce.x += __shfl_xor(acce.x, 8, 64);
    acce.y += __shfl_xor(acce.y, 8, 64);
    acce.z += __shfl_xor(acce.z, 8, 64);
    acce.w += __shfl_xor(acce.w, 8, 64);
    acce.x += __shfl_xor(acce.x, 16, 64);
    acce.y += __shfl_xor(acce.y, 16, 64);
    acce.z += __shfl_xor(acce.z, 16, 64);
    acce.w += __shfl_xor(acce.w, 16, 64);
    acce.x += __shfl_xor(acce.x, 32, 64);
    acce.y += __shfl_xor(acce.y, 32, 64);
    acce.z += __shfl_xor(acce.z, 32, 64);
    acce.w += __shfl_xor(acce.w, 32, 64);

    if (half == 0) {
        float4 wv = *reinterpret_cast<const float4*>(w + q * 4);
        float* o = out + (size_t)g * D_OUT;
        f32x4 r; r.x = accft.x * wv.x; r.y = accft.y * wv.y;
                 r.z = accft.z * wv.z; r.w = accft.w * wv.w;
        __builtin_nontemporal_store(r, reinterpret_cast<f32x4*>(o + q * 4));
        if (q < 8) {
            f32x4 re; re.x = acce.x; re.y = acce.y; re.z = acce.z; re.w = acce.w;
            __builtin_nontemporal_store(re, reinterpret_cast<f32x4*>(o + D_FT + q * 4));
        }
    }
}

// ---- fallback (R1 atomic path) if ws too small ----
__global__ void scatter_ft_kernel(const float* __restrict__ emb, const float* __restrict__ w,
                                  const int* __restrict__ src_idx, const int* __restrict__ dst_idx,
                                  float* __restrict__ out, int n_items) {
    int idx = blockIdx.x * blockDim.x + threadIdx.x;
    if (idx >= n_items) return;
    int e = idx >> 5, q = idx & 31;
    int s = src_idx[e], d = dst_idx[e];
    const float4 v  = *reinterpret_cast<const float4*>(emb + (size_t)s * D_FT + q * 4);
    const float4 wv = *reinterpret_cast<const float4*>(w + q * 4);
    float* o = out + (size_t)d * D_OUT + q * 4;
    atomicAdd(o + 0, v.x * wv.x); atomicAdd(o + 1, v.y * wv.y);
    atomicAdd(o + 2, v.z * wv.z); atomicAdd(o + 3, v.w * wv.w);
}
__global__ void scatter_e_kernel(const float* __restrict__ e_feat, const int* __restrict__ dst_idx,
                                 float* __restrict__ out, int n_items) {
    int idx = blockIdx.x * blockDim.x + threadIdx.x;
    if (idx >= n_items) return;
    int e = idx >> 3, q = idx & 7;
    int d = dst_idx[e];
    const float4 v = *reinterpret_cast<const float4*>(e_feat + (size_t)e * D_E + q * 4);
    float* o = out + (size_t)d * D_OUT + D_FT + q * 4;
    atomicAdd(o + 0, v.x); atomicAdd(o + 1, v.y);
    atomicAdd(o + 2, v.z); atomicAdd(o + 3, v.w);
}

extern "C" void kernel_launch(void* const* d_in, const int* in_sizes, int n_in,
                              void* d_out, int out_size, void* d_ws, size_t ws_size,
                              hipStream_t stream) {
    const float* emb    = (const float*)d_in[0];   // [N, 128]
    const float* e_feat = (const float*)d_in[1];   // [E, 32]
    const float* w      = (const float*)d_in[2];   // [1, 128]
    const int*   src    = (const int*)d_in[3];     // [E]
    const int*   dst    = (const int*)d_in[4];     // [E]
    float* out = (float*)d_out;                    // [N, 160]

    const int E = in_sizes[3];
    const int N = out_size / D_OUT;

    // ws layout: cursor[N] | ovf_cnt[1] | pad[1] | bucket[N*CAP] i32x2 | ovf[E]
    size_t ints_head = (size_t)N + 2;
    size_t need = ints_head * 4 + (size_t)N * CAP * 8 + (size_t)E * 4;

    if (ws_size >= need) {
        int*   cursor  = (int*)d_ws;
        int*   ovf_cnt = cursor + N;
        i32x2* bucket  = (i32x2*)(cursor + ints_head);
        int*   ovf     = (int*)(bucket + (size_t)N * CAP);

        hipMemsetAsync(cursor, 0, ints_head * sizeof(int), stream);
        place_bucket_kernel<<<(E + 255) / 256, 256, 0, stream>>>(
            src, dst, cursor, bucket, ovf, ovf_cnt, E);
        gather_bucket_kernel<<<((size_t)N * 64 + 255) / 256, 256, 0, stream>>>(
            emb, e_feat, w, cursor, bucket, src, dst, ovf, ovf_cnt, out, N);
    } else {
        hipMemsetAsync(d_out, 0, (size_t)out_size * sizeof(float), stream);
        int items_ft = E * 32, items_e = E * 8;
        scatter_ft_kernel<<<(items_ft + 255) / 256, 256, 0, stream>>>(emb, w, src, dst, out, items_ft);
        scatter_e_kernel<<<(items_e + 255) / 256, 256, 0, stream>>>(e_feat, dst, out, items_e);
    }
}